// Round 13
// baseline (354.773 us; speedup 1.0000x reference)
//
#include <hip/hip_runtime.h>
#include <hip/hip_bf16.h>

#define N_TOK 2048
#define DMODEL 1024
#define NEXP 8
#define FFDIM 4096
#define NMAX 2048
#define PADROWS 5120
#define TMAX 40

#define BM 128
#define BN 128
#define BK 64
#define KSPL 4

typedef __attribute__((ext_vector_type(8))) short s16x8;
typedef __attribute__((ext_vector_type(4))) float f32x4;

__device__ __forceinline__ float bf2f(ushort u) {
    union { uint i; float f; } x; x.i = ((uint)u) << 16; return x.f;
}
__device__ __forceinline__ ushort f2bf(float f) {
    union { float f; uint i; } x; x.f = f;
    uint r = x.i + 0x7fffu + ((x.i >> 16) & 1u);
    return (ushort)(r >> 16);
}

__device__ __forceinline__ void gl_lds16(const void* g, void* l) {
    __builtin_amdgcn_global_load_lds(
        (const __attribute__((address_space(1))) unsigned int*)g,
        (__attribute__((address_space(3))) unsigned int*)l, 16, 0, 0);
}

__device__ __forceinline__ float block_sum(float v, float* s4) {
    #pragma unroll
    for (int off = 32; off; off >>= 1) v += __shfl_down(v, off);
    __syncthreads();
    if ((threadIdx.x & 63) == 0) s4[threadIdx.x >> 6] = v;
    __syncthreads();
    return s4[0] + s4[1] + s4[2] + s4[3];
}

// ---------------- Router ----------------
__global__ __launch_bounds__(256)
void router_kernel(const float* __restrict__ x, const float* __restrict__ gate_w,
                   ushort* __restrict__ norm, float* __restrict__ scores,
                   int* __restrict__ cnt, int* __restrict__ lists,
                   int4* __restrict__ info, float2* __restrict__ gpair) {
    __shared__ float s4[4];
    const int n = blockIdx.x, tid = threadIdx.x;
    const float* xr = x + (size_t)n * DMODEL;
    float4 v = *(const float4*)(xr + tid * 4);

    float tot = block_sum(v.x + v.y + v.z + v.w, s4);
    float mu = tot * (1.0f / DMODEL);
    float d0 = v.x - mu, d1 = v.y - mu, d2 = v.z - mu, d3 = v.w - mu;
    float var = block_sum(d0 * d0 + d1 * d1 + d2 * d2 + d3 * d3, s4) * (1.0f / DMODEL);
    float rstd = rsqrtf(var + 1e-6f);

    ushort nb[4] = { f2bf(d0 * rstd), f2bf(d1 * rstd), f2bf(d2 * rstd), f2bf(d3 * rstd) };
    *(uint2*)(norm + (size_t)n * DMODEL + tid * 4) = *(uint2*)nb;

    float lg[NEXP];
    #pragma unroll
    for (int e = 0; e < NEXP; ++e) {
        float4 g = *(const float4*)(gate_w + (size_t)e * DMODEL + tid * 4);
        lg[e] = v.x * g.x + v.y * g.y + v.z * g.z + v.w * g.w;
    }
    #pragma unroll
    for (int e = 0; e < NEXP; ++e) lg[e] = block_sum(lg[e], s4);

    if (tid == 0) {
        float m = lg[0];
        #pragma unroll
        for (int e = 1; e < NEXP; ++e) m = fmaxf(m, lg[e]);
        float ex[NEXP], Z = 0.f;
        #pragma unroll
        for (int e = 0; e < NEXP; ++e) { ex[e] = expf(lg[e] - m); Z += ex[e]; }
        float inv = 1.0f / Z;
        float sc[NEXP];
        #pragma unroll
        for (int e = 0; e < NEXP; ++e) { sc[e] = ex[e] * inv; scores[n * NEXP + e] = sc[e]; }
        int i1 = 0;
        #pragma unroll
        for (int e = 1; e < NEXP; ++e) if (sc[e] > sc[i1]) i1 = e;
        int i2 = (i1 == 0) ? 1 : 0;
        #pragma unroll
        for (int e = 0; e < NEXP; ++e) if (e != i1 && sc[e] > sc[i2]) i2 = e;
        int s1 = atomicAdd(&cnt[i1], 1);
        lists[i1 * NMAX + s1] = n;
        int s2 = atomicAdd(&cnt[i2], 1);
        lists[i2 * NMAX + s2] = n;
        info[n] = make_int4(i1, s1, i2, s2);
        gpair[n] = make_float2(sc[i1], sc[i2]);
    }
}

// ------- Prep: aux loss + padded offsets + row-tile map -------
__global__ __launch_bounds__(256)
void prep_kernel(const float* __restrict__ scores, const int* __restrict__ cnt,
                 int* __restrict__ offs_pad, int* __restrict__ ntiles,
                 int4* __restrict__ tilemap, float* __restrict__ aux_out) {
    __shared__ float s4[4];
    __shared__ float imp[NEXP];
    float part[NEXP] = {};
    for (int i = threadIdx.x; i < N_TOK; i += 256) {
        #pragma unroll
        for (int e = 0; e < NEXP; ++e) part[e] += scores[i * NEXP + e];
    }
    #pragma unroll
    for (int e = 0; e < NEXP; ++e) {
        float s = block_sum(part[e], s4);
        if (threadIdx.x == 0) imp[e] = s;
    }
    __syncthreads();
    if (threadIdx.x == 0) {
        float aux = 0.f; int pad = 0, idx = 0;
        #pragma unroll
        for (int e = 0; e < NEXP; ++e) {
            aux += imp[e] * (float)cnt[e];
            offs_pad[e] = pad;
            int tiles = (cnt[e] + BM - 1) / BM;
            for (int t = 0; t < tiles; ++t)
                tilemap[idx++] = make_int4(e, pad + t * BM, 0, 0);
            pad += tiles * BM;
        }
        offs_pad[NEXP] = pad;
        ntiles[0] = idx;
        aux_out[0] = aux * (float)NEXP / ((float)N_TOK * (float)N_TOK);
    }
}

// ------- Gather into padded grouped layout; zero pad rows -------
__global__ __launch_bounds__(256)
void gather_kernel(const ushort* __restrict__ norm, const float* __restrict__ ln_g,
                   const float* __restrict__ ln_b, const int* __restrict__ offs_pad,
                   const int* __restrict__ cnt, const int* __restrict__ lists,
                   ushort* __restrict__ A1) {
    const int r = blockIdx.x;
    int e = 0;
    #pragma unroll
    for (int k = 1; k < NEXP; ++k) if (r >= offs_pad[k]) e = k;
    const int slot = r - offs_pad[e];
    const int t4 = threadIdx.x * 4;
    if (slot >= cnt[e]) {
        ushort z[4] = {};
        *(uint2*)(A1 + (size_t)r * DMODEL + t4) = *(uint2*)z;
        return;
    }
    const int token = lists[e * NMAX + slot];
    uint2 nbv = *(const uint2*)(norm + (size_t)token * DMODEL + t4);
    ushort ns[4]; *(uint2*)ns = nbv;
    float4 gv = *(const float4*)(ln_g + (size_t)e * DMODEL + t4);
    float4 bv = *(const float4*)(ln_b + (size_t)e * DMODEL + t4);
    ushort ob[4] = { f2bf(bf2f(ns[0]) * gv.x + bv.x), f2bf(bf2f(ns[1]) * gv.y + bv.y),
                     f2bf(bf2f(ns[2]) * gv.z + bv.z), f2bf(bf2f(ns[3]) * gv.w + bv.w) };
    *(uint2*)(A1 + (size_t)r * DMODEL + t4) = *(uint2*)ob;
}

// ------- Grouped GEMM: depth-3 counted-vmcnt pipeline (T4), 512 thr, 144 KB LDS -----
// Triple-buffered A(bf16)+W(f32) via gl_lds. Per wave per stage: 2 A + 4 W = 6 loads.
// Loop top: s_waitcnt vmcnt(12) (retire tile-t's 6; tiles t+1/t+2 stay IN FLIGHT
// across the barriers) -> s_barrier -> MFMA(t%3) -> s_barrier -> stage(t+3).
// Fully unrolled so buffer indices are compile-time; sched_barrier(0) pins regions.
template<int KDIM, int NT, int KSPLT, bool RELU>
__global__ __launch_bounds__(512, 1)
void moe_gemm(const ushort* __restrict__ A, const float* __restrict__ W,
              const float* __restrict__ bias, const int* __restrict__ ntiles,
              const int4* __restrict__ tilemap, ushort* __restrict__ hout,
              float* __restrict__ yout) {
    __shared__ ushort As[3][BM * BK];   // 3 x 16 KB
    __shared__ float  Wsf[3][BN * BK];  // 3 x 32 KB  -> 144 KB total
    constexpr int NOUT = NT * BN;

    const int q = (int)gridDim.x >> 3;
    const int logical = ((int)blockIdx.x & 7) * q + ((int)blockIdx.x >> 3);
    const int bt = logical % TMAX;
    int g = logical / TMAX;
    if (bt >= ntiles[0]) return;
    const int nt = g % NT;
    const int kb = g / NT;
    const int4 tm = tilemap[bt];
    const int e = tm.x, row0 = tm.y;

    const int tid = threadIdx.x, lane = tid & 63, wave = tid >> 6;
    const int wm = (wave >> 2) * 64;    // 2 wave-rows
    const int wn = (wave & 3) * 32;     // 4 wave-cols

    const ushort* Agb = A + (size_t)row0 * KDIM;
    const float*  Wgb = W + ((size_t)e * NOUT + nt * BN) * KDIM;

    f32x4 acc[4][2] = {};

    auto stageA = [&](int step, int b) {
        #pragma unroll
        for (int i = 0; i < 2; ++i) {
            const int c = wave * 128 + i * 64 + lane;      // chunk 0..1023
            const int row = c >> 3;
            const int scolx = (((c & 7) ^ (row & 7)) * 8);
            gl_lds16(Agb + (size_t)row * KDIM + step * BK + scolx,
                     &As[b][(wave * 128 + i * 64) * 8]);
        }
    };
    auto stageW = [&](int step, int b) {
        #pragma unroll
        for (int i = 0; i < 4; ++i) {
            const int c = wave * 256 + i * 64 + lane;      // chunk 0..2047
            const int row = c >> 4;
            const int scol = (c & 15) ^ (row & 7);         // 16B-chunk source col
            gl_lds16(Wgb + (size_t)row * KDIM + step * BK + scol * 4,
                     &Wsf[b][(wave * 256 + i * 64) * 4]);
        }
    };
    auto readW = [&](int b, int ni, int kki) -> s16x8 {
        const int row = wn + ni * 16 + (lane & 15);
        const int x = row & 7;
        const int cb = kki * 8 + (lane >> 4) * 2;
        const float4 f0 = *(const float4*)&Wsf[b][row * 64 + ((cb ^ x) << 2)];
        const float4 f1 = *(const float4*)&Wsf[b][row * 64 + (((cb + 1) ^ x) << 2)];
        union { s16x8 v; __hip_bfloat162 h2[4]; } u;
        u.h2[0] = __float22bfloat162_rn(make_float2(f0.x, f0.y));
        u.h2[1] = __float22bfloat162_rn(make_float2(f0.z, f0.w));
        u.h2[2] = __float22bfloat162_rn(make_float2(f1.x, f1.y));
        u.h2[3] = __float22bfloat162_rn(make_float2(f1.z, f1.w));
        return u.v;
    };
    auto mfma_phase = [&](int b) {
        #pragma unroll
        for (int kki = 0; kki < 2; ++kki) {
            const int cx = (kki * 32 + (lane >> 4) * 8) ^ ((lane & 7) << 3);
            s16x8 af[4], bfv[2];
            #pragma unroll
            for (int mi = 0; mi < 4; ++mi)
                af[mi] = *(const s16x8*)&As[b][(wm + mi * 16 + (lane & 15)) * BK + cx];
            #pragma unroll
            for (int ni = 0; ni < 2; ++ni)
                bfv[ni] = readW(b, ni, kki);
            #pragma unroll
            for (int mi = 0; mi < 4; ++mi)
                #pragma unroll
                for (int ni = 0; ni < 2; ++ni)
                    acc[mi][ni] = __builtin_amdgcn_mfma_f32_16x16x32_bf16(
                        af[mi], bfv[ni], acc[mi][ni], 0, 0, 0);
        }
    };

    const int KS = KDIM / BK / KSPLT;   // 16 for both GEMMs
    const int kt0 = kb * KS;

    // prologue: fill 3 buffers (18 loads/wave outstanding)
    stageA(kt0 + 0, 0); stageW(kt0 + 0, 0);
    stageA(kt0 + 1, 1); stageW(kt0 + 1, 1);
    stageA(kt0 + 2, 2); stageW(kt0 + 2, 2);
    __builtin_amdgcn_sched_barrier(0);

    #pragma unroll
    for (int s = 0; s < 16; ++s) {
        asm volatile("s_waitcnt vmcnt(12)" ::: "memory");  // tile s landed; s+1,s+2 in flight
        __builtin_amdgcn_sched_barrier(0);
        __builtin_amdgcn_s_barrier();                      // buffer s%3 complete for all waves
        __builtin_amdgcn_sched_barrier(0);
        mfma_phase(s % 3);
        __builtin_amdgcn_sched_barrier(0);
        __builtin_amdgcn_s_barrier();                      // all reads of s%3 done (WAR)
        __builtin_amdgcn_sched_barrier(0);
        const int nxt = (s + 3 < 16) ? (kt0 + s + 3) : (kt0 + 15);  // clamp: harmless restage
        stageA(nxt, s % 3);
        stageW(nxt, s % 3);
        __builtin_amdgcn_sched_barrier(0);
    }
    asm volatile("s_waitcnt vmcnt(0)" ::: "memory");       // drain before exit

    if (RELU) {
        #pragma unroll
        for (int ni = 0; ni < 2; ++ni) {
            const int nn = nt * BN + wn + ni * 16 + (lane & 15);
            const float bv = bias[(size_t)e * NOUT + nn];
            #pragma unroll
            for (int mi = 0; mi < 4; ++mi)
                #pragma unroll
                for (int r = 0; r < 4; ++r) {
                    const int sl = wm + mi * 16 + ((lane >> 4) << 2) + r;
                    hout[(size_t)(row0 + sl) * NOUT + nn] =
                        f2bf(fmaxf(acc[mi][ni][r] + bv, 0.f));
                }
        }
    } else {
        #pragma unroll
        for (int ni = 0; ni < 2; ++ni) {
            const int nn = nt * BN + wn + ni * 16 + (lane & 15);
            #pragma unroll
            for (int mi = 0; mi < 4; ++mi)
                #pragma unroll
                for (int r = 0; r < 4; ++r) {
                    const int sl = wm + mi * 16 + ((lane >> 4) << 2) + r;
                    yout[((size_t)kb * PADROWS + row0 + sl) * NOUT + nn] = acc[mi][ni][r];
                }
        }
    }
}

// ------- Combine -------
__global__ __launch_bounds__(256)
void combine_kernel(const float* __restrict__ ypart, const float* __restrict__ b2,
                    const float* __restrict__ x, const int* __restrict__ offs_pad,
                    const int4* __restrict__ info, const float2* __restrict__ gpair,
                    float* __restrict__ out) {
    const int n = blockIdx.x, d = threadIdx.x * 4;
    const int4 ii = info[n];
    const float2 g = gpair[n];
    const int r1 = offs_pad[ii.x] + ii.y, r2 = offs_pad[ii.z] + ii.w;
    f32x4 y1 = {}, y2 = {};
    #pragma unroll
    for (int kb = 0; kb < KSPL; ++kb) {
        y1 += *(const f32x4*)(ypart + ((size_t)kb * PADROWS + r1) * DMODEL + d);
        y2 += *(const f32x4*)(ypart + ((size_t)kb * PADROWS + r2) * DMODEL + d);
    }
    const f32x4 b21 = *(const f32x4*)(b2 + (size_t)ii.x * DMODEL + d);
    const f32x4 b22 = *(const f32x4*)(b2 + (size_t)ii.z * DMODEL + d);
    const f32x4 xv  = *(const f32x4*)(x + (size_t)n * DMODEL + d);
    f32x4 o = g.x * (y1 + b21 + xv) + g.y * (y2 + b22 + xv);
    *(f32x4*)(out + (size_t)n * DMODEL + d) = o;
}

extern "C" void kernel_launch(void* const* d_in, const int* in_sizes, int n_in,
                              void* d_out, int out_size, void* d_ws, size_t ws_size,
                              hipStream_t stream) {
    const float* x      = (const float*)d_in[0];
    const float* gate_w = (const float*)d_in[1];
    const float* ln_g   = (const float*)d_in[2];
    const float* ln_b   = (const float*)d_in[3];
    const float* w1     = (const float*)d_in[4];
    const float* b1     = (const float*)d_in[5];
    const float* w2     = (const float*)d_in[6];
    const float* b2     = (const float*)d_in[7];
    float* out = (float*)d_out;

    char* w = (char*)d_ws;
    int*    cnt      = (int*)(w + 0);
    int*    offs_pad = (int*)(w + 64);
    int*    ntiles   = (int*)(w + 128);
    int4*   tilemap  = (int4*)(w + 192);
    int*    lists    = (int*)(w + 1024);
    float*  scores   = (float*)(w + 66560);
    int4*   info     = (int4*)(w + 132096);
    float2* gpair    = (float2*)(w + 164864);
    ushort* norm     = (ushort*)(w + 181248);
    ushort* A1       = (ushort*)(w + 4375552);
    ushort* h        = (ushort*)(w + 14861312);
    float*  ypart    = (float*)(w + 56804352);

    hipMemsetAsync(cnt, 0, 64, stream);

    router_kernel<<<N_TOK, 256, 0, stream>>>(x, gate_w, norm, scores, cnt, lists, info, gpair);
    prep_kernel<<<1, 256, 0, stream>>>(scores, cnt, offs_pad, ntiles, tilemap,
                                       out + (size_t)N_TOK * DMODEL);
    gather_kernel<<<PADROWS, 256, 0, stream>>>(norm, ln_g, ln_b, offs_pad, cnt, lists, A1);
    moe_gemm<DMODEL, FFDIM / BN, 1, true><<<TMAX * (FFDIM / BN), 512, 0, stream>>>(
        A1, w1, b1, ntiles, tilemap, h, nullptr);
    moe_gemm<FFDIM, DMODEL / BN, KSPL, false><<<TMAX * (DMODEL / BN) * KSPL, 512, 0, stream>>>(
        h, w2, nullptr, ntiles, tilemap, nullptr, ypart);
    combine_kernel<<<N_TOK, 256, 0, stream>>>(ypart, b2, x, offs_pad, info, gpair, out);
}

// Round 14
// 322.830 us; speedup vs baseline: 1.0989x; 1.0989x over previous
//
#include <hip/hip_runtime.h>
#include <hip/hip_bf16.h>

#define N_TOK 2048
#define DMODEL 1024
#define NEXP 8
#define FFDIM 4096
#define NMAX 2048
#define PADROWS 6144
#define TMAX 24

#define BM 256
#define BN 256
#define BK 64
#define KSPL 4

typedef __attribute__((ext_vector_type(8))) short s16x8;
typedef __attribute__((ext_vector_type(4))) float f32x4;

__device__ __forceinline__ float bf2f(ushort u) {
    union { uint i; float f; } x; x.i = ((uint)u) << 16; return x.f;
}
__device__ __forceinline__ ushort f2bf(float f) {
    union { float f; uint i; } x; x.f = f;
    uint r = x.i + 0x7fffu + ((x.i >> 16) & 1u);
    return (ushort)(r >> 16);
}

__device__ __forceinline__ void gl_lds16(const void* g, void* l) {
    __builtin_amdgcn_global_load_lds(
        (const __attribute__((address_space(1))) unsigned int*)g,
        (__attribute__((address_space(3))) unsigned int*)l, 16, 0, 0);
}

__device__ __forceinline__ float block_sum(float v, float* s4) {
    #pragma unroll
    for (int off = 32; off; off >>= 1) v += __shfl_down(v, off);
    __syncthreads();
    if ((threadIdx.x & 63) == 0) s4[threadIdx.x >> 6] = v;
    __syncthreads();
    return s4[0] + s4[1] + s4[2] + s4[3];
}

// ---------------- Router ----------------
__global__ __launch_bounds__(256)
void router_kernel(const float* __restrict__ x, const float* __restrict__ gate_w,
                   ushort* __restrict__ norm, float* __restrict__ scores,
                   int* __restrict__ cnt, int* __restrict__ lists,
                   int4* __restrict__ info, float2* __restrict__ gpair) {
    __shared__ float s4[4];
    const int n = blockIdx.x, tid = threadIdx.x;
    const float* xr = x + (size_t)n * DMODEL;
    float4 v = *(const float4*)(xr + tid * 4);

    float tot = block_sum(v.x + v.y + v.z + v.w, s4);
    float mu = tot * (1.0f / DMODEL);
    float d0 = v.x - mu, d1 = v.y - mu, d2 = v.z - mu, d3 = v.w - mu;
    float var = block_sum(d0 * d0 + d1 * d1 + d2 * d2 + d3 * d3, s4) * (1.0f / DMODEL);
    float rstd = rsqrtf(var + 1e-6f);

    ushort nb[4] = { f2bf(d0 * rstd), f2bf(d1 * rstd), f2bf(d2 * rstd), f2bf(d3 * rstd) };
    *(uint2*)(norm + (size_t)n * DMODEL + tid * 4) = *(uint2*)nb;

    float lg[NEXP];
    #pragma unroll
    for (int e = 0; e < NEXP; ++e) {
        float4 g = *(const float4*)(gate_w + (size_t)e * DMODEL + tid * 4);
        lg[e] = v.x * g.x + v.y * g.y + v.z * g.z + v.w * g.w;
    }
    #pragma unroll
    for (int e = 0; e < NEXP; ++e) lg[e] = block_sum(lg[e], s4);

    if (tid == 0) {
        float m = lg[0];
        #pragma unroll
        for (int e = 1; e < NEXP; ++e) m = fmaxf(m, lg[e]);
        float ex[NEXP], Z = 0.f;
        #pragma unroll
        for (int e = 0; e < NEXP; ++e) { ex[e] = expf(lg[e] - m); Z += ex[e]; }
        float inv = 1.0f / Z;
        float sc[NEXP];
        #pragma unroll
        for (int e = 0; e < NEXP; ++e) { sc[e] = ex[e] * inv; scores[n * NEXP + e] = sc[e]; }
        int i1 = 0;
        #pragma unroll
        for (int e = 1; e < NEXP; ++e) if (sc[e] > sc[i1]) i1 = e;
        int i2 = (i1 == 0) ? 1 : 0;
        #pragma unroll
        for (int e = 0; e < NEXP; ++e) if (e != i1 && sc[e] > sc[i2]) i2 = e;
        int s1 = atomicAdd(&cnt[i1], 1);
        lists[i1 * NMAX + s1] = n;
        int s2 = atomicAdd(&cnt[i2], 1);
        lists[i2 * NMAX + s2] = n;
        info[n] = make_int4(i1, s1, i2, s2);
        gpair[n] = make_float2(sc[i1], sc[i2]);
    }
}

// ------- Prep: aux loss + 256-aligned padded offsets + row-tile map -------
__global__ __launch_bounds__(256)
void prep_kernel(const float* __restrict__ scores, const int* __restrict__ cnt,
                 int* __restrict__ offs_pad, int* __restrict__ ntiles,
                 int4* __restrict__ tilemap, float* __restrict__ aux_out) {
    __shared__ float s4[4];
    __shared__ float imp[NEXP];
    float part[NEXP] = {};
    for (int i = threadIdx.x; i < N_TOK; i += 256) {
        #pragma unroll
        for (int e = 0; e < NEXP; ++e) part[e] += scores[i * NEXP + e];
    }
    #pragma unroll
    for (int e = 0; e < NEXP; ++e) {
        float s = block_sum(part[e], s4);
        if (threadIdx.x == 0) imp[e] = s;
    }
    __syncthreads();
    if (threadIdx.x == 0) {
        float aux = 0.f; int pad = 0, idx = 0;
        #pragma unroll
        for (int e = 0; e < NEXP; ++e) {
            aux += imp[e] * (float)cnt[e];
            offs_pad[e] = pad;
            int tiles = (cnt[e] + BM - 1) / BM;
            for (int t = 0; t < tiles; ++t)
                tilemap[idx++] = make_int4(e, pad + t * BM, 0, 0);
            pad += tiles * BM;
        }
        offs_pad[NEXP] = pad;
        ntiles[0] = idx;
        aux_out[0] = aux * (float)NEXP / ((float)N_TOK * (float)N_TOK);
    }
}

// ------- Gather into padded grouped layout; zero pad rows -------
__global__ __launch_bounds__(256)
void gather_kernel(const ushort* __restrict__ norm, const float* __restrict__ ln_g,
                   const float* __restrict__ ln_b, const int* __restrict__ offs_pad,
                   const int* __restrict__ cnt, const int* __restrict__ lists,
                   ushort* __restrict__ A1) {
    const int r = blockIdx.x;
    int e = 0;
    #pragma unroll
    for (int k = 1; k < NEXP; ++k) if (r >= offs_pad[k]) e = k;
    const int slot = r - offs_pad[e];
    const int t4 = threadIdx.x * 4;
    if (slot >= cnt[e]) {
        ushort z[4] = {};
        *(uint2*)(A1 + (size_t)r * DMODEL + t4) = *(uint2*)z;
        return;
    }
    const int token = lists[e * NMAX + slot];
    uint2 nbv = *(const uint2*)(norm + (size_t)token * DMODEL + t4);
    ushort ns[4]; *(uint2*)ns = nbv;
    float4 gv = *(const float4*)(ln_g + (size_t)e * DMODEL + t4);
    float4 bv = *(const float4*)(ln_b + (size_t)e * DMODEL + t4);
    ushort ob[4] = { f2bf(bf2f(ns[0]) * gv.x + bv.x), f2bf(bf2f(ns[1]) * gv.y + bv.y),
                     f2bf(bf2f(ns[2]) * gv.z + bv.z), f2bf(bf2f(ns[3]) * gv.w + bv.w) };
    *(uint2*)(A1 + (size_t)r * DMODEL + t4) = *(uint2*)ob;
}

// ------- Grouped GEMM: 256x256 tile (4x arithmetic intensity vs 128^2) -------
// 512 thr, 8 waves (2x4), per-wave 128x64 out, acc[8][4]. 96 KB LDS single-buffer.
// R7-proven serial 2-barrier step; staged bytes/FLOP halve -> L2-BW-bound time halves.
// Swizzle/staging/readW math identical to R7/R13 (correctness-verified), rescaled.
template<int KDIM, int NT, int KSPLT, bool RELU>
__global__ __launch_bounds__(512, 1)
void moe_gemm(const ushort* __restrict__ A, const float* __restrict__ W,
              const float* __restrict__ bias, const int* __restrict__ ntiles,
              const int4* __restrict__ tilemap, ushort* __restrict__ hout,
              float* __restrict__ yout) {
    __shared__ ushort As[BM * BK];      // 32 KB bf16
    __shared__ float  Wsf[BN * BK];     // 64 KB f32
    constexpr int NOUT = NT * BN;

    const int q = (int)gridDim.x >> 3;
    const int logical = ((int)blockIdx.x & 7) * q + ((int)blockIdx.x >> 3);
    const int bt = logical % TMAX;      // bt fastest (R7 champion decode)
    int g = logical / TMAX;
    if (bt >= ntiles[0]) return;
    const int nt = g % NT;
    const int kb = g / NT;
    const int4 tm = tilemap[bt];
    const int e = tm.x, row0 = tm.y;

    const int tid = threadIdx.x, lane = tid & 63, wave = tid >> 6;
    const int wm = (wave >> 2) * 128;   // 2 wave-rows of 128
    const int wn = (wave & 3) * 64;     // 4 wave-cols of 64

    const ushort* Agb = A + (size_t)row0 * KDIM;
    const float*  Wgb = W + ((size_t)e * NOUT + nt * BN) * KDIM;

    f32x4 acc[8][4] = {};

    auto stageA = [&](int step) {       // 2048 chunks, 4 per wave-call
        #pragma unroll
        for (int i = 0; i < 4; ++i) {
            const int c = wave * 256 + i * 64 + lane;
            const int row = c >> 3;
            const int scol = (((c & 7) ^ (row & 7)) * 8);
            gl_lds16(Agb + (size_t)row * KDIM + step * BK + scol,
                     &As[(wave * 256 + i * 64) * 8]);
        }
    };
    auto stageW = [&](int step) {       // 4096 chunks, 8 per wave-call
        #pragma unroll
        for (int i = 0; i < 8; ++i) {
            const int c = wave * 512 + i * 64 + lane;
            const int row = c >> 4;
            const int scol = (c & 15) ^ (row & 7);
            gl_lds16(Wgb + (size_t)row * KDIM + step * BK + scol * 4,
                     &Wsf[(wave * 512 + i * 64) * 4]);
        }
    };
    auto readW = [&](int ni, int kki) -> s16x8 {
        const int row = wn + ni * 16 + (lane & 15);
        const int x = row & 7;
        const int cb = kki * 8 + (lane >> 4) * 2;
        const float4 f0 = *(const float4*)&Wsf[row * 64 + ((cb ^ x) << 2)];
        const float4 f1 = *(const float4*)&Wsf[row * 64 + (((cb + 1) ^ x) << 2)];
        union { s16x8 v; __hip_bfloat162 h2[4]; } u;
        u.h2[0] = __float22bfloat162_rn(make_float2(f0.x, f0.y));
        u.h2[1] = __float22bfloat162_rn(make_float2(f0.z, f0.w));
        u.h2[2] = __float22bfloat162_rn(make_float2(f1.x, f1.y));
        u.h2[3] = __float22bfloat162_rn(make_float2(f1.z, f1.w));
        return u.v;
    };
    auto mfma_phase = [&]() {
        #pragma unroll
        for (int kki = 0; kki < 2; ++kki) {
            const int cx = (kki * 32 + (lane >> 4) * 8) ^ ((lane & 7) << 3);
            s16x8 af[8], bfv[4];
            #pragma unroll
            for (int mi = 0; mi < 8; ++mi)
                af[mi] = *(const s16x8*)&As[(wm + mi * 16 + (lane & 15)) * BK + cx];
            #pragma unroll
            for (int ni = 0; ni < 4; ++ni)
                bfv[ni] = readW(ni, kki);
            #pragma unroll
            for (int mi = 0; mi < 8; ++mi)
                #pragma unroll
                for (int ni = 0; ni < 4; ++ni)
                    acc[mi][ni] = __builtin_amdgcn_mfma_f32_16x16x32_bf16(
                        af[mi], bfv[ni], acc[mi][ni], 0, 0, 0);
        }
    };

    const int KS = KDIM / BK / KSPLT;   // 16 for both GEMMs
    const int kt0 = kb * KS;

    for (int s = 0; s < KS; ++s) {
        stageA(kt0 + s);
        stageW(kt0 + s);
        __syncthreads();
        mfma_phase();
        __syncthreads();
    }

    if (RELU) {
        #pragma unroll
        for (int ni = 0; ni < 4; ++ni) {
            const int nn = nt * BN + wn + ni * 16 + (lane & 15);
            const float bv = bias[(size_t)e * NOUT + nn];
            #pragma unroll
            for (int mi = 0; mi < 8; ++mi)
                #pragma unroll
                for (int r = 0; r < 4; ++r) {
                    const int sl = wm + mi * 16 + ((lane >> 4) << 2) + r;
                    hout[(size_t)(row0 + sl) * NOUT + nn] =
                        f2bf(fmaxf(acc[mi][ni][r] + bv, 0.f));
                }
        }
    } else {
        #pragma unroll
        for (int ni = 0; ni < 4; ++ni) {
            const int nn = nt * BN + wn + ni * 16 + (lane & 15);
            #pragma unroll
            for (int mi = 0; mi < 8; ++mi)
                #pragma unroll
                for (int r = 0; r < 4; ++r) {
                    const int sl = wm + mi * 16 + ((lane >> 4) << 2) + r;
                    yout[((size_t)kb * PADROWS + row0 + sl) * NOUT + nn] = acc[mi][ni][r];
                }
        }
    }
}

// ------- Combine -------
__global__ __launch_bounds__(256)
void combine_kernel(const float* __restrict__ ypart, const float* __restrict__ b2,
                    const float* __restrict__ x, const int* __restrict__ offs_pad,
                    const int4* __restrict__ info, const float2* __restrict__ gpair,
                    float* __restrict__ out) {
    const int n = blockIdx.x, d = threadIdx.x * 4;
    const int4 ii = info[n];
    const float2 g = gpair[n];
    const int r1 = offs_pad[ii.x] + ii.y, r2 = offs_pad[ii.z] + ii.w;
    f32x4 y1 = {}, y2 = {};
    #pragma unroll
    for (int kb = 0; kb < KSPL; ++kb) {
        y1 += *(const f32x4*)(ypart + ((size_t)kb * PADROWS + r1) * DMODEL + d);
        y2 += *(const f32x4*)(ypart + ((size_t)kb * PADROWS + r2) * DMODEL + d);
    }
    const f32x4 b21 = *(const f32x4*)(b2 + (size_t)ii.x * DMODEL + d);
    const f32x4 b22 = *(const f32x4*)(b2 + (size_t)ii.z * DMODEL + d);
    const f32x4 xv  = *(const f32x4*)(x + (size_t)n * DMODEL + d);
    f32x4 o = g.x * (y1 + b21 + xv) + g.y * (y2 + b22 + xv);
    *(f32x4*)(out + (size_t)n * DMODEL + d) = o;
}

extern "C" void kernel_launch(void* const* d_in, const int* in_sizes, int n_in,
                              void* d_out, int out_size, void* d_ws, size_t ws_size,
                              hipStream_t stream) {
    const float* x      = (const float*)d_in[0];
    const float* gate_w = (const float*)d_in[1];
    const float* ln_g   = (const float*)d_in[2];
    const float* ln_b   = (const float*)d_in[3];
    const float* w1     = (const float*)d_in[4];
    const float* b1     = (const float*)d_in[5];
    const float* w2     = (const float*)d_in[6];
    const float* b2     = (const float*)d_in[7];
    float* out = (float*)d_out;

    char* w = (char*)d_ws;
    int*    cnt      = (int*)(w + 0);
    int*    offs_pad = (int*)(w + 64);
    int*    ntiles   = (int*)(w + 128);
    int4*   tilemap  = (int4*)(w + 192);
    int*    lists    = (int*)(w + 1024);
    float*  scores   = (float*)(w + 66560);
    int4*   info     = (int4*)(w + 132096);
    float2* gpair    = (float2*)(w + 164864);
    ushort* norm     = (ushort*)(w + 181248);               // 4 MB
    ushort* A1       = (ushort*)(w + 4375552);              // 6144x1024 bf16 = 12.6 MB
    ushort* h        = (ushort*)(w + 16958464);             // 6144x4096 bf16 = 50.3 MB
    float*  ypart    = (float*)(w + 67290112);              // 4x6144x1024 f32 = 100.7 MB

    hipMemsetAsync(cnt, 0, 64, stream);

    router_kernel<<<N_TOK, 256, 0, stream>>>(x, gate_w, norm, scores, cnt, lists, info, gpair);
    prep_kernel<<<1, 256, 0, stream>>>(scores, cnt, offs_pad, ntiles, tilemap,
                                       out + (size_t)N_TOK * DMODEL);
    gather_kernel<<<PADROWS, 256, 0, stream>>>(norm, ln_g, ln_b, offs_pad, cnt, lists, A1);
    moe_gemm<DMODEL, FFDIM / BN, 1, true><<<TMAX * (FFDIM / BN), 512, 0, stream>>>(
        A1, w1, b1, ntiles, tilemap, h, nullptr);
    moe_gemm<FFDIM, DMODEL / BN, KSPL, false><<<TMAX * (DMODEL / BN) * KSPL, 512, 0, stream>>>(
        h, w2, nullptr, ntiles, tilemap, nullptr, ypart);
    combine_kernel<<<N_TOK, 256, 0, stream>>>(ypart, b2, x, offs_pad, info, gpair, out);
}

// Round 15
// 283.809 us; speedup vs baseline: 1.2500x; 1.1375x over previous
//
#include <hip/hip_runtime.h>
#include <hip/hip_bf16.h>

#define N_TOK 2048
#define DMODEL 1024
#define NEXP 8
#define FFDIM 4096
#define NMAX 2048
#define PADROWS 5120
#define TMAX 40

#define BM 128
#define BN 128
#define BK 32
#define KSPL 4

typedef __attribute__((ext_vector_type(8))) short s16x8;
typedef __attribute__((ext_vector_type(4))) float f32x4;

__device__ __forceinline__ float bf2f(ushort u) {
    union { uint i; float f; } x; x.i = ((uint)u) << 16; return x.f;
}
__device__ __forceinline__ ushort f2bf(float f) {
    union { float f; uint i; } x; x.f = f;
    uint r = x.i + 0x7fffu + ((x.i >> 16) & 1u);
    return (ushort)(r >> 16);
}

__device__ __forceinline__ void gl_lds16(const void* g, void* l) {
    __builtin_amdgcn_global_load_lds(
        (const __attribute__((address_space(1))) unsigned int*)g,
        (__attribute__((address_space(3))) unsigned int*)l, 16, 0, 0);
}

__device__ __forceinline__ float wave_sum(float v) {
    #pragma unroll
    for (int off = 32; off; off >>= 1) v += __shfl_xor(v, off);
    return v;
}

__device__ __forceinline__ float block_sum(float v, float* s4) {
    #pragma unroll
    for (int off = 32; off; off >>= 1) v += __shfl_down(v, off);
    __syncthreads();
    if ((threadIdx.x & 63) == 0) s4[threadIdx.x >> 6] = v;
    __syncthreads();
    return s4[0] + s4[1] + s4[2] + s4[3];
}

// ---------------- Router: one WAVE per token, shfl-only reduces ----------------
__global__ __launch_bounds__(256)
void router_kernel(const float* __restrict__ x, const float* __restrict__ gate_w,
                   ushort* __restrict__ norm, float* __restrict__ scores,
                   int* __restrict__ cnt, int* __restrict__ lists,
                   int4* __restrict__ info, float2* __restrict__ gpair) {
    const int wave = threadIdx.x >> 6, lane = threadIdx.x & 63;
    const int n = blockIdx.x * 4 + wave;
    const float* xr = x + (size_t)n * DMODEL + lane * 16;

    float4 v[4];
    #pragma unroll
    for (int j = 0; j < 4; ++j) v[j] = *(const float4*)(xr + j * 4);

    float s = 0.f;
    #pragma unroll
    for (int j = 0; j < 4; ++j) s += v[j].x + v[j].y + v[j].z + v[j].w;
    const float mu = wave_sum(s) * (1.0f / DMODEL);

    float vs = 0.f;
    #pragma unroll
    for (int j = 0; j < 4; ++j) {
        float a = v[j].x - mu, b = v[j].y - mu, c = v[j].z - mu, d = v[j].w - mu;
        vs += a * a + b * b + c * c + d * d;
    }
    const float rstd = rsqrtf(wave_sum(vs) * (1.0f / DMODEL) + 1e-6f);

    ushort nb[16];
    #pragma unroll
    for (int j = 0; j < 4; ++j) {
        nb[j * 4 + 0] = f2bf((v[j].x - mu) * rstd);
        nb[j * 4 + 1] = f2bf((v[j].y - mu) * rstd);
        nb[j * 4 + 2] = f2bf((v[j].z - mu) * rstd);
        nb[j * 4 + 3] = f2bf((v[j].w - mu) * rstd);
    }
    *(uint4*)(norm + (size_t)n * DMODEL + lane * 16)     = *(uint4*)&nb[0];
    *(uint4*)(norm + (size_t)n * DMODEL + lane * 16 + 8) = *(uint4*)&nb[8];

    float lg[NEXP];
    #pragma unroll
    for (int e = 0; e < NEXP; ++e) {
        const float* gw = gate_w + (size_t)e * DMODEL + lane * 16;
        float acc = 0.f;
        #pragma unroll
        for (int j = 0; j < 4; ++j) {
            float4 g = *(const float4*)(gw + j * 4);
            acc += v[j].x * g.x + v[j].y * g.y + v[j].z * g.z + v[j].w * g.w;
        }
        lg[e] = wave_sum(acc);
    }

    if (lane == 0) {
        float m = lg[0];
        #pragma unroll
        for (int e = 1; e < NEXP; ++e) m = fmaxf(m, lg[e]);
        float ex[NEXP], Z = 0.f;
        #pragma unroll
        for (int e = 0; e < NEXP; ++e) { ex[e] = expf(lg[e] - m); Z += ex[e]; }
        float inv = 1.0f / Z;
        float sc[NEXP];
        #pragma unroll
        for (int e = 0; e < NEXP; ++e) { sc[e] = ex[e] * inv; scores[n * NEXP + e] = sc[e]; }
        int i1 = 0;
        #pragma unroll
        for (int e = 1; e < NEXP; ++e) if (sc[e] > sc[i1]) i1 = e;
        int i2 = (i1 == 0) ? 1 : 0;
        #pragma unroll
        for (int e = 0; e < NEXP; ++e) if (e != i1 && sc[e] > sc[i2]) i2 = e;
        int s1 = atomicAdd(&cnt[i1], 1);
        lists[i1 * NMAX + s1] = n;
        int s2 = atomicAdd(&cnt[i2], 1);
        lists[i2 * NMAX + s2] = n;
        info[n] = make_int4(i1, s1, i2, s2);
        gpair[n] = make_float2(sc[i1], sc[i2]);
    }
}

// ------- Prep: aux loss + padded offsets + row-tile map -------
__global__ __launch_bounds__(256)
void prep_kernel(const float* __restrict__ scores, const int* __restrict__ cnt,
                 int* __restrict__ offs_pad, int* __restrict__ ntiles,
                 int4* __restrict__ tilemap, float* __restrict__ aux_out) {
    __shared__ float s4[4];
    __shared__ float imp[NEXP];
    float part[NEXP] = {};
    for (int i = threadIdx.x; i < N_TOK; i += 256) {
        #pragma unroll
        for (int e = 0; e < NEXP; ++e) part[e] += scores[i * NEXP + e];
    }
    #pragma unroll
    for (int e = 0; e < NEXP; ++e) {
        float s = block_sum(part[e], s4);
        if (threadIdx.x == 0) imp[e] = s;
    }
    __syncthreads();
    if (threadIdx.x == 0) {
        float aux = 0.f; int pad = 0, idx = 0;
        #pragma unroll
        for (int e = 0; e < NEXP; ++e) {
            aux += imp[e] * (float)cnt[e];
            offs_pad[e] = pad;
            int tiles = (cnt[e] + BM - 1) / BM;
            for (int t = 0; t < tiles; ++t)
                tilemap[idx++] = make_int4(e, pad + t * BM, 0, 0);
            pad += tiles * BM;
        }
        offs_pad[NEXP] = pad;
        ntiles[0] = idx;
        aux_out[0] = aux * (float)NEXP / ((float)N_TOK * (float)N_TOK);
    }
}

// ------- Gather into padded grouped layout; zero pad rows -------
__global__ __launch_bounds__(256)
void gather_kernel(const ushort* __restrict__ norm, const float* __restrict__ ln_g,
                   const float* __restrict__ ln_b, const int* __restrict__ offs_pad,
                   const int* __restrict__ cnt, const int* __restrict__ lists,
                   ushort* __restrict__ A1) {
    const int r = blockIdx.x;
    int e = 0;
    #pragma unroll
    for (int k = 1; k < NEXP; ++k) if (r >= offs_pad[k]) e = k;
    const int slot = r - offs_pad[e];
    const int t4 = threadIdx.x * 4;
    if (slot >= cnt[e]) {
        ushort z[4] = {};
        *(uint2*)(A1 + (size_t)r * DMODEL + t4) = *(uint2*)z;
        return;
    }
    const int token = lists[e * NMAX + slot];
    uint2 nbv = *(const uint2*)(norm + (size_t)token * DMODEL + t4);
    ushort ns[4]; *(uint2*)ns = nbv;
    float4 gv = *(const float4*)(ln_g + (size_t)e * DMODEL + t4);
    float4 bv = *(const float4*)(ln_b + (size_t)e * DMODEL + t4);
    ushort ob[4] = { f2bf(bf2f(ns[0]) * gv.x + bv.x), f2bf(bf2f(ns[1]) * gv.y + bv.y),
                     f2bf(bf2f(ns[2]) * gv.z + bv.z), f2bf(bf2f(ns[3]) * gv.w + bv.w) };
    *(uint2*)(A1 + (size_t)r * DMODEL + t4) = *(uint2*)ob;
}

// ------- Grouped GEMM: BK=32 DOUBLE-BUFFER + counted vmcnt, 48 KB, 3 blocks/CU ------
// The one untried combination: depth-1 prefetch WITH R7's 3-block co-residency.
// Per step/wave: 2 A + 4 W gl_lds = 6 loads. Iter: stage(t+1,buf^1) -> vmcnt(6)
// (tile t landed; t+1 stays in flight across barriers) -> barrier -> MFMA(buf) ->
// barrier. WAR: buf^1's last readers passed the previous trailing barrier.
// Layouts: As phys chunk p of row r holds logical p^(r&3); Wsf: p^(r&7).
template<int KDIM, int NT, int KSPLT, bool RELU>
__global__ __launch_bounds__(256, 3)
void moe_gemm(const ushort* __restrict__ A, const float* __restrict__ W,
              const float* __restrict__ bias, const int* __restrict__ ntiles,
              const int4* __restrict__ tilemap, ushort* __restrict__ hout,
              float* __restrict__ yout) {
    __shared__ ushort As[2][BM * BK];   // 2 x 8 KB
    __shared__ float  Wsf[2][BN * BK];  // 2 x 16 KB  -> 48 KB total
    constexpr int NOUT = NT * BN;

    const int q = (int)gridDim.x >> 3;
    const int logical = ((int)blockIdx.x & 7) * q + ((int)blockIdx.x >> 3);
    const int bt = logical % TMAX;      // bt fastest (R7 champion decode)
    int g = logical / TMAX;
    if (bt >= ntiles[0]) return;
    const int nt = g % NT;
    const int kb = g / NT;
    const int4 tm = tilemap[bt];
    const int e = tm.x, row0 = tm.y;

    const int tid = threadIdx.x, lane = tid & 63, wave = tid >> 6;
    const int wm = (wave & 1) * 64, wn = (wave >> 1) * 64;

    const ushort* Agb = A + (size_t)row0 * KDIM;
    const float*  Wgb = W + ((size_t)e * NOUT + nt * BN) * KDIM;

    f32x4 acc[4][4] = {};

    auto stageA = [&](int step, int b) {     // 512 chunks, 2 gl_lds/wave
        #pragma unroll
        for (int i = 0; i < 2; ++i) {
            const int c = wave * 128 + i * 64 + lane;
            const int row = c >> 2;                       // 4 chunks/row (32 bf16)
            const int src = ((c & 3) ^ (row & 3)) * 8;    // inverse-swizzled source
            gl_lds16(Agb + (size_t)row * KDIM + step * BK + src,
                     &As[b][(wave * 128 + i * 64) * 8]);
        }
    };
    auto stageW = [&](int step, int b) {     // 1024 chunks, 4 gl_lds/wave
        #pragma unroll
        for (int i = 0; i < 4; ++i) {
            const int c = wave * 256 + i * 64 + lane;
            const int row = c >> 3;                       // 8 chunks/row (32 f32)
            const int src = ((c & 7) ^ (row & 7)) * 4;
            gl_lds16(Wgb + (size_t)row * KDIM + step * BK + src,
                     &Wsf[b][(wave * 256 + i * 64) * 4]);
        }
    };
    auto readW = [&](int b, int ni) -> s16x8 {
        const int row = wn + ni * 16 + (lane & 15);
        const int x = row & 7;
        const int cb = (lane >> 4) * 2;                   // 2 chunks = 8 f32 = K-frag
        const float4 f0 = *(const float4*)&Wsf[b][row * BK + ((cb ^ x) << 2)];
        const float4 f1 = *(const float4*)&Wsf[b][row * BK + (((cb + 1) ^ x) << 2)];
        union { s16x8 v; __hip_bfloat162 h2[4]; } u;
        u.h2[0] = __float22bfloat162_rn(make_float2(f0.x, f0.y));
        u.h2[1] = __float22bfloat162_rn(make_float2(f0.z, f0.w));
        u.h2[2] = __float22bfloat162_rn(make_float2(f1.x, f1.y));
        u.h2[3] = __float22bfloat162_rn(make_float2(f1.z, f1.w));
        return u.v;
    };
    auto mfma_phase = [&](int b) {
        s16x8 af[4], bfv[4];
        #pragma unroll
        for (int mi = 0; mi < 4; ++mi) {
            const int row = wm + mi * 16 + (lane & 15);
            af[mi] = *(const s16x8*)&As[b][row * BK + (((lane >> 4) ^ (row & 3)) * 8)];
        }
        #pragma unroll
        for (int ni = 0; ni < 4; ++ni)
            bfv[ni] = readW(b, ni);
        #pragma unroll
        for (int mi = 0; mi < 4; ++mi)
            #pragma unroll
            for (int ni = 0; ni < 4; ++ni)
                acc[mi][ni] = __builtin_amdgcn_mfma_f32_16x16x32_bf16(
                    af[mi], bfv[ni], acc[mi][ni], 0, 0, 0);
    };

    const int KS = KDIM / BK / KSPLT;   // 32 for both GEMMs
    const int kt0 = kb * KS;

    // prologue: tile 0 -> buf 0 (6 loads/wave outstanding)
    stageA(kt0, 0);
    stageW(kt0, 0);
    __builtin_amdgcn_sched_barrier(0);

    int buf = 0;
    for (int s = 0; s < KS; ++s) {
        const int nxt = (s + 1 < KS) ? (kt0 + s + 1) : (kt0 + s);  // clamped
        stageA(nxt, buf ^ 1);            // 6 more in flight (12 total)
        stageW(nxt, buf ^ 1);
        __builtin_amdgcn_sched_barrier(0);
        asm volatile("s_waitcnt vmcnt(6)" ::: "memory");  // tile s landed; s+1 in flight
        __builtin_amdgcn_sched_barrier(0);
        __builtin_amdgcn_s_barrier();                     // all waves: buf complete
        __builtin_amdgcn_sched_barrier(0);
        mfma_phase(buf);
        __builtin_amdgcn_sched_barrier(0);
        __builtin_amdgcn_s_barrier();                     // reads of buf done (WAR)
        __builtin_amdgcn_sched_barrier(0);
        buf ^= 1;
    }
    asm volatile("s_waitcnt vmcnt(0)" ::: "memory");      // drain before exit

    if (RELU) {
        #pragma unroll
        for (int ni = 0; ni < 4; ++ni) {
            const int nn = nt * BN + wn + ni * 16 + (lane & 15);
            const float bv = bias[(size_t)e * NOUT + nn];
            #pragma unroll
            for (int mi = 0; mi < 4; ++mi)
                #pragma unroll
                for (int r = 0; r < 4; ++r) {
                    const int sl = wm + mi * 16 + ((lane >> 4) << 2) + r;
                    hout[(size_t)(row0 + sl) * NOUT + nn] =
                        f2bf(fmaxf(acc[mi][ni][r] + bv, 0.f));
                }
        }
    } else {
        #pragma unroll
        for (int ni = 0; ni < 4; ++ni) {
            const int nn = nt * BN + wn + ni * 16 + (lane & 15);
            #pragma unroll
            for (int mi = 0; mi < 4; ++mi)
                #pragma unroll
                for (int r = 0; r < 4; ++r) {
                    const int sl = wm + mi * 16 + ((lane >> 4) << 2) + r;
                    yout[((size_t)kb * PADROWS + row0 + sl) * NOUT + nn] = acc[mi][ni][r];
                }
        }
    }
}

// ------- Combine -------
__global__ __launch_bounds__(256)
void combine_kernel(const float* __restrict__ ypart, const float* __restrict__ b2,
                    const float* __restrict__ x, const int* __restrict__ offs_pad,
                    const int4* __restrict__ info, const float2* __restrict__ gpair,
                    float* __restrict__ out) {
    const int n = blockIdx.x, d = threadIdx.x * 4;
    const int4 ii = info[n];
    const float2 g = gpair[n];
    const int r1 = offs_pad[ii.x] + ii.y, r2 = offs_pad[ii.z] + ii.w;
    f32x4 y1 = {}, y2 = {};
    #pragma unroll
    for (int kb = 0; kb < KSPL; ++kb) {
        y1 += *(const f32x4*)(ypart + ((size_t)kb * PADROWS + r1) * DMODEL + d);
        y2 += *(const f32x4*)(ypart + ((size_t)kb * PADROWS + r2) * DMODEL + d);
    }
    const f32x4 b21 = *(const f32x4*)(b2 + (size_t)ii.x * DMODEL + d);
    const f32x4 b22 = *(const f32x4*)(b2 + (size_t)ii.z * DMODEL + d);
    const f32x4 xv  = *(const f32x4*)(x + (size_t)n * DMODEL + d);
    f32x4 o = g.x * (y1 + b21 + xv) + g.y * (y2 + b22 + xv);
    *(f32x4*)(out + (size_t)n * DMODEL + d) = o;
}

extern "C" void kernel_launch(void* const* d_in, const int* in_sizes, int n_in,
                              void* d_out, int out_size, void* d_ws, size_t ws_size,
                              hipStream_t stream) {
    const float* x      = (const float*)d_in[0];
    const float* gate_w = (const float*)d_in[1];
    const float* ln_g   = (const float*)d_in[2];
    const float* ln_b   = (const float*)d_in[3];
    const float* w1     = (const float*)d_in[4];
    const float* b1     = (const float*)d_in[5];
    const float* w2     = (const float*)d_in[6];
    const float* b2     = (const float*)d_in[7];
    float* out = (float*)d_out;

    char* w = (char*)d_ws;
    int*    cnt      = (int*)(w + 0);
    int*    offs_pad = (int*)(w + 64);
    int*    ntiles   = (int*)(w + 128);
    int4*   tilemap  = (int4*)(w + 192);
    int*    lists    = (int*)(w + 1024);
    float*  scores   = (float*)(w + 66560);
    int4*   info     = (int4*)(w + 132096);
    float2* gpair    = (float2*)(w + 164864);
    ushort* norm     = (ushort*)(w + 181248);
    ushort* A1       = (ushort*)(w + 4375552);
    ushort* h        = (ushort*)(w + 14861312);
    float*  ypart    = (float*)(w + 56804352);

    hipMemsetAsync(cnt, 0, 64, stream);

    router_kernel<<<N_TOK / 4, 256, 0, stream>>>(x, gate_w, norm, scores, cnt, lists, info, gpair);
    prep_kernel<<<1, 256, 0, stream>>>(scores, cnt, offs_pad, ntiles, tilemap,
                                       out + (size_t)N_TOK * DMODEL);
    gather_kernel<<<PADROWS, 256, 0, stream>>>(norm, ln_g, ln_b, offs_pad, cnt, lists, A1);
    moe_gemm<DMODEL, FFDIM / BN, 1, true><<<TMAX * (FFDIM / BN), 256, 0, stream>>>(
        A1, w1, b1, ntiles, tilemap, h, nullptr);
    moe_gemm<FFDIM, DMODEL / BN, KSPL, false><<<TMAX * (DMODEL / BN) * KSPL, 256, 0, stream>>>(
        h, w2, nullptr, ntiles, tilemap, nullptr, ypart);
    combine_kernel<<<N_TOK, 256, 0, stream>>>(ypart, b2, x, offs_pad, info, gpair, out);
}